// Round 4
// baseline (344.342 us; speedup 1.0000x reference)
//
#include <hip/hip_runtime.h>
#include <math.h>

#define BB  128
#define NN  1024
#define KNN 40
#define HH  64

__device__ __forceinline__ unsigned mbcnt64(unsigned long long m) {
    return __builtin_amdgcn_mbcnt_hi((unsigned)(m >> 32),
           __builtin_amdgcn_mbcnt_lo((unsigned)(m & 0xffffffffu), 0u));
}

// ---------------------------------------------------------------------------
// Kernel A: 40-NN selection (ballot-popcount bisection on float-as-uint keys)
// + fused MLP max-pool + sigmoid weight. 4 waves/block, 16 rows/block,
// grid = 8192. TWO rows processed interleaved per wave (ILP=2) so the two
// serial chains -- the bisection scalar round-trip and the pool LDS reads --
// overlap each other (R3: VALUBusy 61% @ 43% occupancy = latency-bound).
//
// hi0 = wave-max(per-lane min of 16 keys) + 1: >= 64 elements are <= max of
// per-lane minima, so cnt(hi0) >= 64 >= 40 -- valid upper bracket, saves ~8
// bisection iterations vs starting at +inf.
//
// Pool loop: cbuf padded to 64 with the query point (distance 0 < thr always,
// so it's a duplicate of a selected point -> max unchanged) => fixed 64-trip
// loop, unroll 8, bulk ds_read_b128 issue.
// ---------------------------------------------------------------------------
__global__ __launch_bounds__(256, 4) void knn_weight_kernel(
    const float* __restrict__ pts,  // [B,3,N]
    const float* __restrict__ W1,   // [3,H]
    const float* __restrict__ b1,   // [H]
    const float* __restrict__ W2,   // [H]
    const float* __restrict__ b2,   // [1]
    float* __restrict__ wout)       // [B,N]
{
    __shared__ float4 sp[NN];           // 16 KB: (x,y,z,0)
    __shared__ float4 cbuf[4][2][64];   //  8 KB: per-wave, per-row neighbors

    const int b    = blockIdx.x >> 6;
    const int grp  = blockIdx.x & 63;
    const int tid  = threadIdx.x;
    const int w    = tid >> 6;
    const int lane = tid & 63;

    const float* px = pts + b * 3 * NN;
    for (int i = tid; i < NN; i += 256)
        sp[i] = make_float4(px[i], px[NN + i], px[2 * NN + i], 0.0f);
    __syncthreads();

    const float w1x = W1[lane];           // W1[0][lane]
    const float w1y = W1[HH + lane];      // W1[1][lane]
    const float w1z = W1[2 * HH + lane];  // W1[2][lane]
    const float b1v = b1[lane];
    const float w2v = W2[lane];
    const float b2v = b2[0];

    for (int half = 0; half < 2; ++half) {
        const int n0 = grp * 16 + w * 4 + half * 2;
        const int n1 = n0 + 1;
        const float4 q0 = sp[n0];
        const float4 q1 = sp[n1];

        // --- distances for both rows; one sp read serves both ---
        unsigned k0[16], k1[16];
        unsigned pm0 = 0xffffffffu, pm1 = 0xffffffffu;
        #pragma unroll
        for (int t = 0; t < 16; ++t) {
            const float4 p = sp[t * 64 + lane];
            float dx = p.x - q0.x, dy = p.y - q0.y, dz = p.z - q0.z;
            k0[t] = __float_as_uint(fmaf(dx, dx, fmaf(dy, dy, dz * dz)));
            dx = p.x - q1.x; dy = p.y - q1.y; dz = p.z - q1.z;
            k1[t] = __float_as_uint(fmaf(dx, dx, fmaf(dy, dy, dz * dz)));
            pm0 = pm0 < k0[t] ? pm0 : k0[t];
            pm1 = pm1 < k1[t] ? pm1 : k1[t];
        }
        // wave-max of per-lane minima -> upper bracket for the 40th smallest
        #pragma unroll
        for (int s = 1; s < 64; s <<= 1) {
            const unsigned o0 = (unsigned)__shfl_xor((int)pm0, s);
            const unsigned o1 = (unsigned)__shfl_xor((int)pm1, s);
            pm0 = pm0 > o0 ? pm0 : o0;
            pm1 = pm1 > o1 ? pm1 : o1;
        }

        // --- dual interleaved bisection (independent scalar chains) ---
        unsigned lo0 = 0u, hi0 = pm0 + 1u, thr0 = 0u; int done0 = 0, fnd0 = 0;
        unsigned lo1 = 0u, hi1 = pm1 + 1u, thr1 = 0u; int done1 = 0, fnd1 = 0;
        while (!(done0 && done1)) {
            if (!done0) {
                const unsigned mid = (lo0 + hi0) >> 1;
                int c = 0;
                #pragma unroll
                for (int t = 0; t < 16; ++t)
                    c += (int)__popcll(__ballot(k0[t] < mid));
                if (c == KNN) { thr0 = mid; fnd0 = 1; done0 = 1; }
                else {
                    if (c < KNN) lo0 = mid; else hi0 = mid;
                    done0 = (hi0 - lo0 <= 1u);
                }
            }
            if (!done1) {
                const unsigned mid = (lo1 + hi1) >> 1;
                int c = 0;
                #pragma unroll
                for (int t = 0; t < 16; ++t)
                    c += (int)__popcll(__ballot(k1[t] < mid));
                if (c == KNN) { thr1 = mid; fnd1 = 1; done1 = 1; }
                else {
                    if (c < KNN) lo1 = mid; else hi1 = mid;
                    done1 = (hi1 - lo1 <= 1u);
                }
            }
        }
        if (!fnd0) thr0 = hi0;   // boundary ties: dup-inclusive
        if (!fnd1) thr1 = hi1;

        // --- ballot-scan compaction, both rows ---
        int base0 = 0, base1 = 0;
        #pragma unroll
        for (int t = 0; t < 16; ++t) {
            const float4 p = sp[t * 64 + lane];
            const bool p0 = k0[t] < thr0;
            const unsigned long long bal0 = __ballot(p0);
            if (p0) {
                const int pos = base0 + (int)mbcnt64(bal0);
                if (pos < 64) cbuf[w][0][pos] = p;
            }
            base0 += (int)__popcll(bal0);
            const bool p1 = k1[t] < thr1;
            const unsigned long long bal1 = __ballot(p1);
            if (p1) {
                const int pos = base1 + (int)mbcnt64(bal1);
                if (pos < 64) cbuf[w][1][pos] = p;
            }
            base1 += (int)__popcll(bal1);
        }
        const int mm0 = base0 < 64 ? base0 : 64;
        const int mm1 = base1 < 64 ? base1 : 64;
        // pad to 64 with the query point (always a selected duplicate)
        if (lane >= mm0) cbuf[w][0][lane] = q0;
        if (lane >= mm1) cbuf[w][1][lane] = q1;

        // --- fixed-trip fused MLP max-pool, both rows interleaved ---
        float pool0 = -__builtin_inff(), pool1 = -__builtin_inff();
        #pragma unroll 8
        for (int j = 0; j < 64; ++j) {
            const float4 c0 = cbuf[w][0][j];
            pool0 = fmaxf(pool0, fmaf(c0.x, w1x, fmaf(c0.y, w1y, c0.z * w1z)));
            const float4 c1 = cbuf[w][1][j];
            pool1 = fmaxf(pool1, fmaf(c1.x, w1x, fmaf(c1.y, w1y, c1.z * w1z)));
        }

        // --- sigmoid(relu(pool + b1) @ W2 + b2) ---
        float acc0 = fmaxf(pool0 + b1v, 0.0f) * w2v;
        float acc1 = fmaxf(pool1 + b1v, 0.0f) * w2v;
        #pragma unroll
        for (int s = 1; s < 64; s <<= 1) {
            acc0 += __shfl_xor(acc0, s);
            acc1 += __shfl_xor(acc1, s);
        }
        if (lane == 0) {
            wout[b * NN + n0] = 1.0f / (1.0f + expf(-(acc0 + b2v)));
            wout[b * NN + n1] = 1.0f / (1.0f + expf(-(acc1 + b2v)));
        }
    }
}

// ---------------------------------------------------------------------------
// Kernel B: weighted order-2 jet fit per batch. One block (256 thr) per batch.
// ---------------------------------------------------------------------------
__global__ __launch_bounds__(256) void fit_kernel(
    const float* __restrict__ pts,   // [B,3,N]
    const float* __restrict__ wbuf,  // [B,N]
    float* __restrict__ out)         // [B,3]
{
    const int b    = blockIdx.x;
    const int tid  = threadIdx.x;
    const int lane = tid & 63;
    const int wv   = tid >> 6;
    const float* x    = pts + b * 3 * NN;
    const float* y    = x + NN;
    const float* z    = y + NN;
    const float* wrow = wbuf + b * NN;

    __shared__ float red[4][3];
    __shared__ float red27[4][27];
    __shared__ float sh_h;
    __shared__ int   sh_useW;

    // pass 1: mean|x|, mean|y|, valid_count
    float sax = 0.f, say = 0.f, cnt = 0.f;
    for (int i = tid; i < NN; i += 256) {
        sax += fabsf(x[i]);
        say += fabsf(y[i]);
        if (wrow[i] > 0.001f) cnt += 1.0f;
    }
    #pragma unroll
    for (int s = 1; s < 64; s <<= 1) {
        sax += __shfl_xor(sax, s);
        say += __shfl_xor(say, s);
        cnt += __shfl_xor(cnt, s);
    }
    if (lane == 0) { red[wv][0] = sax; red[wv][1] = say; red[wv][2] = cnt; }
    __syncthreads();
    if (tid == 0) {
        float SX = 0.f, SY = 0.f, C = 0.f;
        for (int q2 = 0; q2 < 4; ++q2) { SX += red[q2][0]; SY += red[q2][1]; C += red[q2][2]; }
        float h = (SX / (float)NN + SY / (float)NN) * 0.5f;
        if (fabsf(h) < 1e-4f) h = 0.1f;
        sh_h    = h;
        sh_useW = (C > 18.5f) ? 1 : 0;   // valid_count > 18
    }
    __syncthreads();
    const float h    = sh_h;
    const int   useW = sh_useW;
    const float ih   = 1.0f / h;

    // pass 2: XtX (21 unique) + XtY (6)
    float S[27];
    #pragma unroll
    for (int i = 0; i < 27; ++i) S[i] = 0.f;

    for (int i = tid; i < NN; i += 256) {
        const float wt = useW ? wrow[i] : 1.0f;
        const float xs = x[i] * ih;
        const float ys = y[i] * ih;
        const float zz = z[i];
        const float A[6] = { xs, ys, xs * xs, ys * ys, xs * ys, 1.0f };
        int c = 0;
        #pragma unroll
        for (int p = 0; p < 6; ++p) {
            const float wp = wt * A[p];
            #pragma unroll
            for (int q2 = p; q2 < 6; ++q2) {
                S[c] = fmaf(wp, A[q2], S[c]);
                ++c;
            }
            S[21 + p] = fmaf(wp, zz, S[21 + p]);
        }
    }
    #pragma unroll
    for (int i = 0; i < 27; ++i) {
        float v = S[i];
        #pragma unroll
        for (int s = 1; s < 64; s <<= 1) v += __shfl_xor(v, s);
        if (lane == 0) red27[wv][i] = v;
    }
    __syncthreads();

    if (tid == 0) {
        double T[27];
        for (int i = 0; i < 27; ++i)
            T[i] = (double)red27[0][i] + (double)red27[1][i]
                 + (double)red27[2][i] + (double)red27[3][i];

        double M[6][7];
        int c = 0;
        for (int p = 0; p < 6; ++p)
            for (int q2 = p; q2 < 6; ++q2) {
                M[p][q2] = T[c]; M[q2][p] = T[c]; ++c;
            }
        for (int p = 0; p < 6; ++p) M[p][6] = T[21 + p];

        // Gaussian elimination with partial pivoting (fp64, single thread)
        for (int col = 0; col < 6; ++col) {
            int piv = col; double best = fabs(M[col][col]);
            for (int rr = col + 1; rr < 6; ++rr) {
                const double a = fabs(M[rr][col]);
                if (a > best) { best = a; piv = rr; }
            }
            if (piv != col)
                for (int cc = col; cc < 7; ++cc) {
                    const double t = M[col][cc]; M[col][cc] = M[piv][cc]; M[piv][cc] = t;
                }
            const double f = 1.0 / M[col][col];
            for (int rr = col + 1; rr < 6; ++rr) {
                const double m = M[rr][col] * f;
                for (int cc = col; cc < 7; ++cc) M[rr][cc] -= m * M[col][cc];
            }
        }
        double beta[6];
        for (int rr = 5; rr >= 0; --rr) {
            double s = M[rr][6];
            for (int cc = rr + 1; cc < 6; ++cc) s -= M[rr][cc] * beta[cc];
            beta[rr] = s / M[rr][rr];
        }
        const double hd  = (double)h;
        const double nx  = -(beta[0] / hd);
        const double ny  = -(beta[1] / hd);
        const double nrm = sqrt(nx * nx + ny * ny + 1.0);
        out[b * 3 + 0] = (float)(nx / nrm);
        out[b * 3 + 1] = (float)(ny / nrm);
        out[b * 3 + 2] = (float)(1.0 / nrm);
    }
}

extern "C" void kernel_launch(void* const* d_in, const int* in_sizes, int n_in,
                              void* d_out, int out_size, void* d_ws, size_t ws_size,
                              hipStream_t stream) {
    const float* pts = (const float*)d_in[0];
    const float* W1  = (const float*)d_in[1];
    const float* b1  = (const float*)d_in[2];
    const float* W2  = (const float*)d_in[3];
    const float* b2  = (const float*)d_in[4];
    // d_in[5] = k (==40), compile-time constant here.
    float* wbuf = (float*)d_ws;   // [B*N] f32 = 512 KB scratch
    float* out  = (float*)d_out;  // [B,3] f32

    knn_weight_kernel<<<BB * (NN / 16), 256, 0, stream>>>(pts, W1, b1, W2, b2, wbuf);
    fit_kernel<<<BB, 256, 0, stream>>>(pts, wbuf, out);
}

// Round 5
// 304.968 us; speedup vs baseline: 1.1291x; 1.1291x over previous
//
#include <hip/hip_runtime.h>
#include <math.h>

#define BB  128
#define NN  1024
#define KNN 40
#define HH  64

__device__ __forceinline__ unsigned mbcnt64(unsigned long long m) {
    return __builtin_amdgcn_mbcnt_hi((unsigned)(m >> 32),
           __builtin_amdgcn_mbcnt_lo((unsigned)(m & 0xffffffffu), 0u));
}

// ---------------------------------------------------------------------------
// Kernel A: 40-NN selection + fused MLP max-pool + sigmoid weight.
// One row per wave pass; 4 waves/block, 16 rows/block, grid = 8192.
//
// R2/R4 lesson: key[16] must stay in VGPRs (spill -> 100s of MB of scratch
// HBM traffic). Single-row shape = ~56 VGPR (R3-verified).
// __launch_bounds__(256,6): cap ~84 VGPR -- headroom so the allocator never
// spills; natural usage <=64 still yields 8 blocks/CU with 20 KB LDS.
//
// Selection: count(pivot) = #{key < pivot} via 16 v_cmp ballots + scalar
// popcounts (wave-uniform). Bracket [wave_min(keys), wave_max(lane mins)+1]
// (cnt(lo)=0 < 40 <= 64 <= cnt(hi) by construction). Pivot chosen by
// false-position interpolation in float space alternated with bisection
// (safeguard); exact exit at cnt==40, dup-inclusive thr=hi at width 1.
// ---------------------------------------------------------------------------
__global__ __launch_bounds__(256, 6) void knn_weight_kernel(
    const float* __restrict__ pts,  // [B,3,N]
    const float* __restrict__ W1,   // [3,H]
    const float* __restrict__ b1,   // [H]
    const float* __restrict__ W2,   // [H]
    const float* __restrict__ b2,   // [1]
    float* __restrict__ wout)       // [B,N]
{
    __shared__ float4 sp[NN];        // 16 KB: (x,y,z,0)
    __shared__ float4 cbuf[4][64];   //  4 KB: per-wave compacted neighbors

    const int b    = blockIdx.x >> 6;
    const int grp  = blockIdx.x & 63;
    const int tid  = threadIdx.x;
    const int w    = tid >> 6;
    const int lane = tid & 63;

    const float* px = pts + b * 3 * NN;
    for (int i = tid; i < NN; i += 256)
        sp[i] = make_float4(px[i], px[NN + i], px[2 * NN + i], 0.0f);
    __syncthreads();

    const float w1x = W1[lane];           // W1[0][lane]
    const float w1y = W1[HH + lane];      // W1[1][lane]
    const float w1z = W1[2 * HH + lane];  // W1[2][lane]
    const float b1v = b1[lane];
    const float w2v = W2[lane];
    const float b2v = b2[0];

    for (int r = 0; r < 4; ++r) {
        const int n = grp * 16 + w * 4 + r;
        const float4 q = sp[n];

        // --- 16 distances per lane as monotone uint keys (stay in VGPRs) ---
        unsigned key[16];
        unsigned lmin = 0xffffffffu;
        #pragma unroll
        for (int t = 0; t < 16; ++t) {
            const float4 p = sp[t * 64 + lane];
            const float dx = p.x - q.x, dy = p.y - q.y, dz = p.z - q.z;
            key[t] = __float_as_uint(fmaf(dx, dx, fmaf(dy, dy, dz * dz)));
            lmin = lmin < key[t] ? lmin : key[t];
        }
        // wave-min of all keys (lo) and wave-max of per-lane minima (hi-1)
        unsigned wmin = lmin, wmaxmin = lmin;
        #pragma unroll
        for (int s = 1; s < 64; s <<= 1) {
            const unsigned a = (unsigned)__shfl_xor((int)wmin, s);
            const unsigned c = (unsigned)__shfl_xor((int)wmaxmin, s);
            wmin    = wmin    < a ? wmin    : a;
            wmaxmin = wmaxmin > c ? wmaxmin : c;
        }

        // --- interpolation/bisection hybrid for the 40-NN threshold ---
        unsigned lo = wmin, hi = wmaxmin + 1u;
        float flo = __uint_as_float(lo), fhi = __uint_as_float(hi);
        float clo = 0.0f, chi = 64.0f;   // chi = lower-bound estimate (safe)
        unsigned thr = 0u;
        int found = 0, it = 0;
        while (hi - lo > 1u) {
            unsigned mid;
            if (it & 1) {
                mid = lo + ((hi - lo) >> 1);              // safeguard step
            } else {
                const float tt = (40.5f - clo) / (chi - clo);
                const float pf = flo + (fhi - flo) * tt;  // false position
                mid = __float_as_uint(pf);
                if (mid <= lo) mid = lo + 1u;
                if (mid >= hi) mid = hi - 1u;
            }
            int c = 0;
            #pragma unroll
            for (int t = 0; t < 16; ++t)
                c += (int)__popcll(__ballot(key[t] < mid));
            if (c == KNN) { thr = mid; found = 1; break; }
            if (c < KNN) { lo = mid; flo = __uint_as_float(mid); clo = (float)c; }
            else         { hi = mid; fhi = __uint_as_float(mid); chi = (float)c; }
            ++it;
        }
        if (!found) thr = hi;   // boundary ties: dup-inclusive

        // --- ballot-scan compaction of passing points into cbuf[w] ---
        int base = 0;
        #pragma unroll
        for (int t = 0; t < 16; ++t) {
            const bool p = key[t] < thr;
            const unsigned long long bal = __ballot(p);
            if (p) {
                const int pos = base + (int)mbcnt64(bal);
                if (pos < 64) cbuf[w][pos] = sp[t * 64 + lane];
            }
            base += (int)__popcll(bal);
        }
        const int mm  = base < 64 ? base : 64;       // >= 40 by invariant
        const int mm4 = (mm + 3) & ~3;               // round up to x4
        if (lane >= mm && lane < mm4) cbuf[w][lane] = q;  // pad: self-dup

        // --- fused MLP max-pool: lane = hidden unit, broadcast LDS reads ---
        float pool = -__builtin_inff();
        for (int j = 0; j < mm4; j += 4) {
            const float4 c0 = cbuf[w][j + 0];
            const float4 c1 = cbuf[w][j + 1];
            const float4 c2 = cbuf[w][j + 2];
            const float4 c3 = cbuf[w][j + 3];
            const float s0 = fmaf(c0.x, w1x, fmaf(c0.y, w1y, c0.z * w1z));
            const float s1 = fmaf(c1.x, w1x, fmaf(c1.y, w1y, c1.z * w1z));
            const float s2 = fmaf(c2.x, w1x, fmaf(c2.y, w1y, c2.z * w1z));
            const float s3 = fmaf(c3.x, w1x, fmaf(c3.y, w1y, c3.z * w1z));
            pool = fmaxf(pool, fmaxf(fmaxf(s0, s1), fmaxf(s2, s3)));
        }

        // --- sigmoid(relu(pool + b1) @ W2 + b2) ---
        float acc = fmaxf(pool + b1v, 0.0f) * w2v;
        #pragma unroll
        for (int s = 1; s < 64; s <<= 1)
            acc += __shfl_xor(acc, s);
        if (lane == 0)
            wout[b * NN + n] = 1.0f / (1.0f + expf(-(acc + b2v)));
    }
}

// ---------------------------------------------------------------------------
// Kernel B: weighted order-2 jet fit per batch. One block (256 thr) per batch.
// ---------------------------------------------------------------------------
__global__ __launch_bounds__(256) void fit_kernel(
    const float* __restrict__ pts,   // [B,3,N]
    const float* __restrict__ wbuf,  // [B,N]
    float* __restrict__ out)         // [B,3]
{
    const int b    = blockIdx.x;
    const int tid  = threadIdx.x;
    const int lane = tid & 63;
    const int wv   = tid >> 6;
    const float* x    = pts + b * 3 * NN;
    const float* y    = x + NN;
    const float* z    = y + NN;
    const float* wrow = wbuf + b * NN;

    __shared__ float red[4][3];
    __shared__ float red27[4][27];
    __shared__ float sh_h;
    __shared__ int   sh_useW;

    // pass 1: mean|x|, mean|y|, valid_count
    float sax = 0.f, say = 0.f, cnt = 0.f;
    for (int i = tid; i < NN; i += 256) {
        sax += fabsf(x[i]);
        say += fabsf(y[i]);
        if (wrow[i] > 0.001f) cnt += 1.0f;
    }
    #pragma unroll
    for (int s = 1; s < 64; s <<= 1) {
        sax += __shfl_xor(sax, s);
        say += __shfl_xor(say, s);
        cnt += __shfl_xor(cnt, s);
    }
    if (lane == 0) { red[wv][0] = sax; red[wv][1] = say; red[wv][2] = cnt; }
    __syncthreads();
    if (tid == 0) {
        float SX = 0.f, SY = 0.f, C = 0.f;
        for (int q2 = 0; q2 < 4; ++q2) { SX += red[q2][0]; SY += red[q2][1]; C += red[q2][2]; }
        float h = (SX / (float)NN + SY / (float)NN) * 0.5f;
        if (fabsf(h) < 1e-4f) h = 0.1f;
        sh_h    = h;
        sh_useW = (C > 18.5f) ? 1 : 0;   // valid_count > 18
    }
    __syncthreads();
    const float h    = sh_h;
    const int   useW = sh_useW;
    const float ih   = 1.0f / h;

    // pass 2: XtX (21 unique) + XtY (6)
    float S[27];
    #pragma unroll
    for (int i = 0; i < 27; ++i) S[i] = 0.f;

    for (int i = tid; i < NN; i += 256) {
        const float wt = useW ? wrow[i] : 1.0f;
        const float xs = x[i] * ih;
        const float ys = y[i] * ih;
        const float zz = z[i];
        const float A[6] = { xs, ys, xs * xs, ys * ys, xs * ys, 1.0f };
        int c = 0;
        #pragma unroll
        for (int p = 0; p < 6; ++p) {
            const float wp = wt * A[p];
            #pragma unroll
            for (int q2 = p; q2 < 6; ++q2) {
                S[c] = fmaf(wp, A[q2], S[c]);
                ++c;
            }
            S[21 + p] = fmaf(wp, zz, S[21 + p]);
        }
    }
    #pragma unroll
    for (int i = 0; i < 27; ++i) {
        float v = S[i];
        #pragma unroll
        for (int s = 1; s < 64; s <<= 1) v += __shfl_xor(v, s);
        if (lane == 0) red27[wv][i] = v;
    }
    __syncthreads();

    if (tid == 0) {
        double T[27];
        for (int i = 0; i < 27; ++i)
            T[i] = (double)red27[0][i] + (double)red27[1][i]
                 + (double)red27[2][i] + (double)red27[3][i];

        double M[6][7];
        int c = 0;
        for (int p = 0; p < 6; ++p)
            for (int q2 = p; q2 < 6; ++q2) {
                M[p][q2] = T[c]; M[q2][p] = T[c]; ++c;
            }
        for (int p = 0; p < 6; ++p) M[p][6] = T[21 + p];

        // Gaussian elimination with partial pivoting (fp64, single thread)
        for (int col = 0; col < 6; ++col) {
            int piv = col; double best = fabs(M[col][col]);
            for (int rr = col + 1; rr < 6; ++rr) {
                const double a = fabs(M[rr][col]);
                if (a > best) { best = a; piv = rr; }
            }
            if (piv != col)
                for (int cc = col; cc < 7; ++cc) {
                    const double t = M[col][cc]; M[col][cc] = M[piv][cc]; M[piv][cc] = t;
                }
            const double f = 1.0 / M[col][col];
            for (int rr = col + 1; rr < 6; ++rr) {
                const double m = M[rr][col] * f;
                for (int cc = col; cc < 7; ++cc) M[rr][cc] -= m * M[col][cc];
            }
        }
        double beta[6];
        for (int rr = 5; rr >= 0; --rr) {
            double s = M[rr][6];
            for (int cc = rr + 1; cc < 6; ++cc) s -= M[rr][cc] * beta[cc];
            beta[rr] = s / M[rr][rr];
        }
        const double hd  = (double)h;
        const double nx  = -(beta[0] / hd);
        const double ny  = -(beta[1] / hd);
        const double nrm = sqrt(nx * nx + ny * ny + 1.0);
        out[b * 3 + 0] = (float)(nx / nrm);
        out[b * 3 + 1] = (float)(ny / nrm);
        out[b * 3 + 2] = (float)(1.0 / nrm);
    }
}

extern "C" void kernel_launch(void* const* d_in, const int* in_sizes, int n_in,
                              void* d_out, int out_size, void* d_ws, size_t ws_size,
                              hipStream_t stream) {
    const float* pts = (const float*)d_in[0];
    const float* W1  = (const float*)d_in[1];
    const float* b1  = (const float*)d_in[2];
    const float* W2  = (const float*)d_in[3];
    const float* b2  = (const float*)d_in[4];
    // d_in[5] = k (==40), compile-time constant here.
    float* wbuf = (float*)d_ws;   // [B*N] f32 = 512 KB scratch
    float* out  = (float*)d_out;  // [B,3] f32

    knn_weight_kernel<<<BB * (NN / 16), 256, 0, stream>>>(pts, W1, b1, W2, b2, wbuf);
    fit_kernel<<<BB, 256, 0, stream>>>(pts, wbuf, out);
}

// Round 6
// 283.541 us; speedup vs baseline: 1.2144x; 1.0756x over previous
//
#include <hip/hip_runtime.h>
#include <math.h>

#define BB  128
#define NN  1024
#define KNN 40
#define HH  64

__device__ __forceinline__ unsigned mbcnt64(unsigned long long m) {
    return __builtin_amdgcn_mbcnt_hi((unsigned)(m >> 32),
           __builtin_amdgcn_mbcnt_lo((unsigned)(m & 0xffffffffu), 0u));
}

// ---------------------------------------------------------------------------
// Kernel A: 40-NN selection + fused MLP max-pool + sigmoid weight.
// One row per wave pass; 4 waves/block, 16 rows/block, grid = 8192.
//
// REGISTER SHAPE IS LOAD-BEARING (R2/R4/R5 post-mortems): key[16] must stay
// in VGPRs. Only __launch_bounds__(256,4) (VGPR cap 128) avoids spills with
// this body -- R3 measured 56 VGPR / zero scratch. (256,6) and (256,8) both
// spilled (hundreds of MB of HBM scratch traffic). Do not tighten.
//
// Selection: count(pivot) = #{key < pivot} via 16 v_cmp ballots + scalar
// popcounts (wave-uniform). Bracket [wave_min(keys), wave_max(lane mins)+1]
// (cnt(lo)=0 < 40 <= 64 <= cnt(hi) by construction). Pivot chosen by
// false-position interpolation in float space alternated with bisection
// (safeguard); exact exit at cnt==40, dup-inclusive thr=hi at width 1.
// ---------------------------------------------------------------------------
__global__ __launch_bounds__(256, 4) void knn_weight_kernel(
    const float* __restrict__ pts,  // [B,3,N]
    const float* __restrict__ W1,   // [3,H]
    const float* __restrict__ b1,   // [H]
    const float* __restrict__ W2,   // [H]
    const float* __restrict__ b2,   // [1]
    float* __restrict__ wout)       // [B,N]
{
    __shared__ float4 sp[NN];        // 16 KB: (x,y,z,0)
    __shared__ float4 cbuf[4][64];   //  4 KB: per-wave compacted neighbors

    const int b    = blockIdx.x >> 6;
    const int grp  = blockIdx.x & 63;
    const int tid  = threadIdx.x;
    const int w    = tid >> 6;
    const int lane = tid & 63;

    const float* px = pts + b * 3 * NN;
    for (int i = tid; i < NN; i += 256)
        sp[i] = make_float4(px[i], px[NN + i], px[2 * NN + i], 0.0f);
    __syncthreads();

    const float w1x = W1[lane];           // W1[0][lane]
    const float w1y = W1[HH + lane];      // W1[1][lane]
    const float w1z = W1[2 * HH + lane];  // W1[2][lane]
    const float b1v = b1[lane];
    const float w2v = W2[lane];
    const float b2v = b2[0];

    for (int r = 0; r < 4; ++r) {
        const int n = grp * 16 + w * 4 + r;
        const float4 q = sp[n];

        // --- 16 distances per lane as monotone uint keys (stay in VGPRs) ---
        unsigned key[16];
        unsigned lmin = 0xffffffffu;
        #pragma unroll
        for (int t = 0; t < 16; ++t) {
            const float4 p = sp[t * 64 + lane];
            const float dx = p.x - q.x, dy = p.y - q.y, dz = p.z - q.z;
            key[t] = __float_as_uint(fmaf(dx, dx, fmaf(dy, dy, dz * dz)));
            lmin = lmin < key[t] ? lmin : key[t];
        }
        // wave-min of all keys (lo) and wave-max of per-lane minima (hi-1)
        unsigned wmin = lmin, wmaxmin = lmin;
        #pragma unroll
        for (int s = 1; s < 64; s <<= 1) {
            const unsigned a = (unsigned)__shfl_xor((int)wmin, s);
            const unsigned c = (unsigned)__shfl_xor((int)wmaxmin, s);
            wmin    = wmin    < a ? wmin    : a;
            wmaxmin = wmaxmin > c ? wmaxmin : c;
        }

        // --- interpolation/bisection hybrid for the 40-NN threshold ---
        unsigned lo = wmin, hi = wmaxmin + 1u;
        float flo = __uint_as_float(lo), fhi = __uint_as_float(hi);
        float clo = 0.0f, chi = 64.0f;   // chi = lower-bound estimate (safe)
        unsigned thr = 0u;
        int found = 0, it = 0;
        while (hi - lo > 1u) {
            unsigned mid;
            if (it & 1) {
                mid = lo + ((hi - lo) >> 1);              // safeguard step
            } else {
                const float tt = (40.5f - clo) / (chi - clo);
                const float pf = flo + (fhi - flo) * tt;  // false position
                mid = __float_as_uint(pf);
                if (mid <= lo) mid = lo + 1u;
                if (mid >= hi) mid = hi - 1u;
            }
            int c = 0;
            #pragma unroll
            for (int t = 0; t < 16; ++t)
                c += (int)__popcll(__ballot(key[t] < mid));
            if (c == KNN) { thr = mid; found = 1; break; }
            if (c < KNN) { lo = mid; flo = __uint_as_float(mid); clo = (float)c; }
            else         { hi = mid; fhi = __uint_as_float(mid); chi = (float)c; }
            ++it;
        }
        if (!found) thr = hi;   // boundary ties: dup-inclusive

        // --- ballot-scan compaction of passing points into cbuf[w] ---
        int base = 0;
        #pragma unroll
        for (int t = 0; t < 16; ++t) {
            const bool p = key[t] < thr;
            const unsigned long long bal = __ballot(p);
            if (p) {
                const int pos = base + (int)mbcnt64(bal);
                if (pos < 64) cbuf[w][pos] = sp[t * 64 + lane];
            }
            base += (int)__popcll(bal);
        }
        const int mm  = base < 64 ? base : 64;       // >= 40 by invariant
        const int mm4 = (mm + 3) & ~3;               // round up to x4
        if (lane >= mm && lane < mm4) cbuf[w][lane] = q;  // pad: self-dup

        // --- fused MLP max-pool: lane = hidden unit, broadcast LDS reads ---
        float pool = -__builtin_inff();
        for (int j = 0; j < mm4; j += 4) {
            const float4 c0 = cbuf[w][j + 0];
            const float4 c1 = cbuf[w][j + 1];
            const float4 c2 = cbuf[w][j + 2];
            const float4 c3 = cbuf[w][j + 3];
            const float s0 = fmaf(c0.x, w1x, fmaf(c0.y, w1y, c0.z * w1z));
            const float s1 = fmaf(c1.x, w1x, fmaf(c1.y, w1y, c1.z * w1z));
            const float s2 = fmaf(c2.x, w1x, fmaf(c2.y, w1y, c2.z * w1z));
            const float s3 = fmaf(c3.x, w1x, fmaf(c3.y, w1y, c3.z * w1z));
            pool = fmaxf(pool, fmaxf(fmaxf(s0, s1), fmaxf(s2, s3)));
        }

        // --- sigmoid(relu(pool + b1) @ W2 + b2) ---
        float acc = fmaxf(pool + b1v, 0.0f) * w2v;
        #pragma unroll
        for (int s = 1; s < 64; s <<= 1)
            acc += __shfl_xor(acc, s);
        if (lane == 0)
            wout[b * NN + n] = 1.0f / (1.0f + expf(-(acc + b2v)));
    }
}

// ---------------------------------------------------------------------------
// Kernel B: weighted order-2 jet fit per batch. One block (256 thr) per batch.
// ---------------------------------------------------------------------------
__global__ __launch_bounds__(256) void fit_kernel(
    const float* __restrict__ pts,   // [B,3,N]
    const float* __restrict__ wbuf,  // [B,N]
    float* __restrict__ out)         // [B,3]
{
    const int b    = blockIdx.x;
    const int tid  = threadIdx.x;
    const int lane = tid & 63;
    const int wv   = tid >> 6;
    const float* x    = pts + b * 3 * NN;
    const float* y    = x + NN;
    const float* z    = y + NN;
    const float* wrow = wbuf + b * NN;

    __shared__ float red[4][3];
    __shared__ float red27[4][27];
    __shared__ float sh_h;
    __shared__ int   sh_useW;

    // pass 1: mean|x|, mean|y|, valid_count
    float sax = 0.f, say = 0.f, cnt = 0.f;
    for (int i = tid; i < NN; i += 256) {
        sax += fabsf(x[i]);
        say += fabsf(y[i]);
        if (wrow[i] > 0.001f) cnt += 1.0f;
    }
    #pragma unroll
    for (int s = 1; s < 64; s <<= 1) {
        sax += __shfl_xor(sax, s);
        say += __shfl_xor(say, s);
        cnt += __shfl_xor(cnt, s);
    }
    if (lane == 0) { red[wv][0] = sax; red[wv][1] = say; red[wv][2] = cnt; }
    __syncthreads();
    if (tid == 0) {
        float SX = 0.f, SY = 0.f, C = 0.f;
        for (int q2 = 0; q2 < 4; ++q2) { SX += red[q2][0]; SY += red[q2][1]; C += red[q2][2]; }
        float h = (SX / (float)NN + SY / (float)NN) * 0.5f;
        if (fabsf(h) < 1e-4f) h = 0.1f;
        sh_h    = h;
        sh_useW = (C > 18.5f) ? 1 : 0;   // valid_count > 18
    }
    __syncthreads();
    const float h    = sh_h;
    const int   useW = sh_useW;
    const float ih   = 1.0f / h;

    // pass 2: XtX (21 unique) + XtY (6)
    float S[27];
    #pragma unroll
    for (int i = 0; i < 27; ++i) S[i] = 0.f;

    for (int i = tid; i < NN; i += 256) {
        const float wt = useW ? wrow[i] : 1.0f;
        const float xs = x[i] * ih;
        const float ys = y[i] * ih;
        const float zz = z[i];
        const float A[6] = { xs, ys, xs * xs, ys * ys, xs * ys, 1.0f };
        int c = 0;
        #pragma unroll
        for (int p = 0; p < 6; ++p) {
            const float wp = wt * A[p];
            #pragma unroll
            for (int q2 = p; q2 < 6; ++q2) {
                S[c] = fmaf(wp, A[q2], S[c]);
                ++c;
            }
            S[21 + p] = fmaf(wp, zz, S[21 + p]);
        }
    }
    #pragma unroll
    for (int i = 0; i < 27; ++i) {
        float v = S[i];
        #pragma unroll
        for (int s = 1; s < 64; s <<= 1) v += __shfl_xor(v, s);
        if (lane == 0) red27[wv][i] = v;
    }
    __syncthreads();

    if (tid == 0) {
        double T[27];
        for (int i = 0; i < 27; ++i)
            T[i] = (double)red27[0][i] + (double)red27[1][i]
                 + (double)red27[2][i] + (double)red27[3][i];

        double M[6][7];
        int c = 0;
        for (int p = 0; p < 6; ++p)
            for (int q2 = p; q2 < 6; ++q2) {
                M[p][q2] = T[c]; M[q2][p] = T[c]; ++c;
            }
        for (int p = 0; p < 6; ++p) M[p][6] = T[21 + p];

        // Gaussian elimination with partial pivoting (fp64, single thread)
        for (int col = 0; col < 6; ++col) {
            int piv = col; double best = fabs(M[col][col]);
            for (int rr = col + 1; rr < 6; ++rr) {
                const double a = fabs(M[rr][col]);
                if (a > best) { best = a; piv = rr; }
            }
            if (piv != col)
                for (int cc = col; cc < 7; ++cc) {
                    const double t = M[col][cc]; M[col][cc] = M[piv][cc]; M[piv][cc] = t;
                }
            const double f = 1.0 / M[col][col];
            for (int rr = col + 1; rr < 6; ++rr) {
                const double m = M[rr][col] * f;
                for (int cc = col; cc < 7; ++cc) M[rr][cc] -= m * M[col][cc];
            }
        }
        double beta[6];
        for (int rr = 5; rr >= 0; --rr) {
            double s = M[rr][6];
            for (int cc = rr + 1; cc < 6; ++cc) s -= M[rr][cc] * beta[cc];
            beta[rr] = s / M[rr][rr];
        }
        const double hd  = (double)h;
        const double nx  = -(beta[0] / hd);
        const double ny  = -(beta[1] / hd);
        const double nrm = sqrt(nx * nx + ny * ny + 1.0);
        out[b * 3 + 0] = (float)(nx / nrm);
        out[b * 3 + 1] = (float)(ny / nrm);
        out[b * 3 + 2] = (float)(1.0 / nrm);
    }
}

extern "C" void kernel_launch(void* const* d_in, const int* in_sizes, int n_in,
                              void* d_out, int out_size, void* d_ws, size_t ws_size,
                              hipStream_t stream) {
    const float* pts = (const float*)d_in[0];
    const float* W1  = (const float*)d_in[1];
    const float* b1  = (const float*)d_in[2];
    const float* W2  = (const float*)d_in[3];
    const float* b2  = (const float*)d_in[4];
    // d_in[5] = k (==40), compile-time constant here.
    float* wbuf = (float*)d_ws;   // [B*N] f32 = 512 KB scratch
    float* out  = (float*)d_out;  // [B,3] f32

    knn_weight_kernel<<<BB * (NN / 16), 256, 0, stream>>>(pts, W1, b1, W2, b2, wbuf);
    fit_kernel<<<BB, 256, 0, stream>>>(pts, wbuf, out);
}

// Round 7
// 274.143 us; speedup vs baseline: 1.2561x; 1.0343x over previous
//
#include <hip/hip_runtime.h>
#include <math.h>

#define BB  128
#define NN  1024
#define KNN 40
#define HH  64

// ---------------------------------------------------------------------------
// Kernel A: 40-NN selection + fused MLP max-pool + sigmoid weight.
// 4 waves/block, 16 rows/block (4 rows/wave), grid = 8192.
//
// REGISTER SHAPE IS LOAD-BEARING (R2/R4/R5 post-mortems): key[16] must stay
// in VGPRs; empirical allocator law on this stack: VGPR budget = 256/arg2.
// Only __launch_bounds__(256,4) (budget 64) fits this body. Do not tighten.
//
// Selection: count(pivot) = #{key < pivot} via 16 v_cmp ballots + scalar
// popcounts. Bracket [0, wave_max(lane mins)+1]. False-position pivots with
// a bisection safeguard every 3rd step; exact exit at cnt==40; dup-inclusive
// thr=hi at interval width 1.
//
// Selected set carried as 16 wave-uniform u64 ballot masks (SGPR pairs, no
// LDS compaction). Pool(row r-1) -- serial uniform broadcast reads -- is
// software-pipelined into the distance fill of row r (register-disjoint:
// keys are dead once masks are built). Epilogue reduce of r-1 sits after
// the mask build of r, overlapping the next merged loop.
// ---------------------------------------------------------------------------
__global__ __launch_bounds__(256, 4) void knn_weight_kernel(
    const float* __restrict__ pts,  // [B,3,N]
    const float* __restrict__ W1,   // [3,H]
    const float* __restrict__ b1,   // [H]
    const float* __restrict__ W2,   // [H]
    const float* __restrict__ b2,   // [1]
    float* __restrict__ wout)       // [B,N]
{
    __shared__ float4 sp[NN];   // 16 KB: (x,y,z,0)

    const int b    = blockIdx.x >> 6;
    const int grp  = blockIdx.x & 63;
    const int tid  = threadIdx.x;
    const int w    = tid >> 6;
    const int lane = tid & 63;

    const float* px = pts + b * 3 * NN;
    for (int i = tid; i < NN; i += 256)
        sp[i] = make_float4(px[i], px[NN + i], px[2 * NN + i], 0.0f);
    __syncthreads();

    const float w1x = W1[lane];           // W1[0][lane]
    const float w1y = W1[HH + lane];      // W1[1][lane]
    const float w1z = W1[2 * HH + lane];  // W1[2][lane]
    const float b1v = b1[lane];
    const float w2v = W2[lane];
    const float b2v = b2[0];

    unsigned long long msk[16];           // wave-uniform ballots (SGPR pairs)
    #pragma unroll
    for (int t = 0; t < 16; ++t) msk[t] = 0ull;

    float poolP = -__builtin_inff();      // pool accumulator for prev row
    int   nP    = -1;                     // prev row id (-1 = none yet)

    for (int r = 0; r < 4; ++r) {
        const int n = grp * 16 + w * 4 + r;
        const float4 q = sp[n];

        // --- merged: pool(prev row, from masks) + distances(current row) ---
        unsigned key[16];
        unsigned lmin = 0xffffffffu;
        #pragma unroll
        for (int t = 0; t < 16; ++t) {
            const float4 pc = sp[t * 64 + lane];    // per-lane vector load
            unsigned long long m = msk[t];          // uniform: pool prev row
            while (m) {
                const int i0 = (int)__ffsll(m) - 1; m &= m - 1;
                int i1 = -1;
                if (m) { i1 = (int)__ffsll(m) - 1; m &= m - 1; }
                const float4 c0 = sp[t * 64 + i0];  // uniform broadcast read
                poolP = fmaxf(poolP, fmaf(c0.x, w1x, fmaf(c0.y, w1y, c0.z * w1z)));
                if (i1 >= 0) {
                    const float4 c1 = sp[t * 64 + i1];
                    poolP = fmaxf(poolP, fmaf(c1.x, w1x, fmaf(c1.y, w1y, c1.z * w1z)));
                }
            }
            const float dx = pc.x - q.x, dy = pc.y - q.y, dz = pc.z - q.z;
            key[t] = __float_as_uint(fmaf(dx, dx, fmaf(dy, dy, dz * dz)));
            lmin = lmin < key[t] ? lmin : key[t];
        }

        // wave-max of per-lane minima -> upper bracket (cnt >= 64 >= 40)
        unsigned wmaxmin = lmin;
        #pragma unroll
        for (int s = 1; s < 64; s <<= 1) {
            const unsigned o = (unsigned)__shfl_xor((int)wmaxmin, s);
            wmaxmin = wmaxmin > o ? wmaxmin : o;
        }

        // --- false-position + periodic-bisection for the 40-NN threshold ---
        unsigned lo = 0u, hi = wmaxmin + 1u;
        float flo = 0.0f, fhi = __uint_as_float(hi);
        float clo = 0.0f, chi = 64.0f;    // chi: safe lower-bound estimate
        unsigned thr = 0u;
        int found = 0, ph = 0;
        while (hi - lo > 1u) {
            unsigned mid;
            if (ph == 2) {                          // every 3rd: safeguard
                mid = lo + ((hi - lo) >> 1);
                ph = 0;
            } else {
                const float tt = (40.5f - clo) / (chi - clo);
                const float pf = flo + (fhi - flo) * tt;
                mid = __float_as_uint(pf);
                if (mid <= lo) mid = lo + 1u;
                if (mid >= hi) mid = hi - 1u;
                ++ph;
            }
            int c = 0;
            #pragma unroll
            for (int t = 0; t < 16; ++t)
                c += (int)__popcll(__ballot(key[t] < mid));
            if (c == KNN) { thr = mid; found = 1; break; }
            if (c < KNN) { lo = mid; flo = __uint_as_float(mid); clo = (float)c; }
            else         { hi = mid; fhi = __uint_as_float(mid); chi = (float)c; }
        }
        if (!found) thr = hi;   // boundary ties: dup-inclusive

        // --- selection masks for this row (consumed next iter / tail) ---
        #pragma unroll
        for (int t = 0; t < 16; ++t)
            msk[t] = __ballot(key[t] < thr);

        // --- finish prev row: sigmoid(relu(pool+b1)@W2 + b2) ---
        if (nP >= 0) {
            float acc = fmaxf(poolP + b1v, 0.0f) * w2v;
            #pragma unroll
            for (int s = 1; s < 64; s <<= 1) acc += __shfl_xor(acc, s);
            if (lane == 0)
                wout[b * NN + nP] = 1.0f / (1.0f + expf(-(acc + b2v)));
        }
        poolP = -__builtin_inff();
        nP = n;
    }

    // --- tail: pool + finish for the last row ---
    #pragma unroll
    for (int t = 0; t < 16; ++t) {
        unsigned long long m = msk[t];
        while (m) {
            const int i0 = (int)__ffsll(m) - 1; m &= m - 1;
            int i1 = -1;
            if (m) { i1 = (int)__ffsll(m) - 1; m &= m - 1; }
            const float4 c0 = sp[t * 64 + i0];
            poolP = fmaxf(poolP, fmaf(c0.x, w1x, fmaf(c0.y, w1y, c0.z * w1z)));
            if (i1 >= 0) {
                const float4 c1 = sp[t * 64 + i1];
                poolP = fmaxf(poolP, fmaf(c1.x, w1x, fmaf(c1.y, w1y, c1.z * w1z)));
            }
        }
    }
    {
        float acc = fmaxf(poolP + b1v, 0.0f) * w2v;
        #pragma unroll
        for (int s = 1; s < 64; s <<= 1) acc += __shfl_xor(acc, s);
        if (lane == 0)
            wout[b * NN + nP] = 1.0f / (1.0f + expf(-(acc + b2v)));
    }
}

// ---------------------------------------------------------------------------
// Kernel B: weighted order-2 jet fit per batch. One block (256 thr) per batch.
// ---------------------------------------------------------------------------
__global__ __launch_bounds__(256) void fit_kernel(
    const float* __restrict__ pts,   // [B,3,N]
    const float* __restrict__ wbuf,  // [B,N]
    float* __restrict__ out)         // [B,3]
{
    const int b    = blockIdx.x;
    const int tid  = threadIdx.x;
    const int lane = tid & 63;
    const int wv   = tid >> 6;
    const float* x    = pts + b * 3 * NN;
    const float* y    = x + NN;
    const float* z    = y + NN;
    const float* wrow = wbuf + b * NN;

    __shared__ float red[4][3];
    __shared__ float red27[4][27];
    __shared__ float sh_h;
    __shared__ int   sh_useW;

    // pass 1: mean|x|, mean|y|, valid_count
    float sax = 0.f, say = 0.f, cnt = 0.f;
    for (int i = tid; i < NN; i += 256) {
        sax += fabsf(x[i]);
        say += fabsf(y[i]);
        if (wrow[i] > 0.001f) cnt += 1.0f;
    }
    #pragma unroll
    for (int s = 1; s < 64; s <<= 1) {
        sax += __shfl_xor(sax, s);
        say += __shfl_xor(say, s);
        cnt += __shfl_xor(cnt, s);
    }
    if (lane == 0) { red[wv][0] = sax; red[wv][1] = say; red[wv][2] = cnt; }
    __syncthreads();
    if (tid == 0) {
        float SX = 0.f, SY = 0.f, C = 0.f;
        for (int q2 = 0; q2 < 4; ++q2) { SX += red[q2][0]; SY += red[q2][1]; C += red[q2][2]; }
        float h = (SX / (float)NN + SY / (float)NN) * 0.5f;
        if (fabsf(h) < 1e-4f) h = 0.1f;
        sh_h    = h;
        sh_useW = (C > 18.5f) ? 1 : 0;   // valid_count > 18
    }
    __syncthreads();
    const float h    = sh_h;
    const int   useW = sh_useW;
    const float ih   = 1.0f / h;

    // pass 2: XtX (21 unique) + XtY (6)
    float S[27];
    #pragma unroll
    for (int i = 0; i < 27; ++i) S[i] = 0.f;

    for (int i = tid; i < NN; i += 256) {
        const float wt = useW ? wrow[i] : 1.0f;
        const float xs = x[i] * ih;
        const float ys = y[i] * ih;
        const float zz = z[i];
        const float A[6] = { xs, ys, xs * xs, ys * ys, xs * ys, 1.0f };
        int c = 0;
        #pragma unroll
        for (int p = 0; p < 6; ++p) {
            const float wp = wt * A[p];
            #pragma unroll
            for (int q2 = p; q2 < 6; ++q2) {
                S[c] = fmaf(wp, A[q2], S[c]);
                ++c;
            }
            S[21 + p] = fmaf(wp, zz, S[21 + p]);
        }
    }
    #pragma unroll
    for (int i = 0; i < 27; ++i) {
        float v = S[i];
        #pragma unroll
        for (int s = 1; s < 64; s <<= 1) v += __shfl_xor(v, s);
        if (lane == 0) red27[wv][i] = v;
    }
    __syncthreads();

    if (tid == 0) {
        double T[27];
        for (int i = 0; i < 27; ++i)
            T[i] = (double)red27[0][i] + (double)red27[1][i]
                 + (double)red27[2][i] + (double)red27[3][i];

        double M[6][7];
        int c = 0;
        for (int p = 0; p < 6; ++p)
            for (int q2 = p; q2 < 6; ++q2) {
                M[p][q2] = T[c]; M[q2][p] = T[c]; ++c;
            }
        for (int p = 0; p < 6; ++p) M[p][6] = T[21 + p];

        // Gaussian elimination with partial pivoting (fp64, single thread)
        for (int col = 0; col < 6; ++col) {
            int piv = col; double best = fabs(M[col][col]);
            for (int rr = col + 1; rr < 6; ++rr) {
                const double a = fabs(M[rr][col]);
                if (a > best) { best = a; piv = rr; }
            }
            if (piv != col)
                for (int cc = col; cc < 7; ++cc) {
                    const double t = M[col][cc]; M[col][cc] = M[piv][cc]; M[piv][cc] = t;
                }
            const double f = 1.0 / M[col][col];
            for (int rr = col + 1; rr < 6; ++rr) {
                const double m = M[rr][col] * f;
                for (int cc = col; cc < 7; ++cc) M[rr][cc] -= m * M[col][cc];
            }
        }
        double beta[6];
        for (int rr = 5; rr >= 0; --rr) {
            double s = M[rr][6];
            for (int cc = rr + 1; cc < 6; ++cc) s -= M[rr][cc] * beta[cc];
            beta[rr] = s / M[rr][rr];
        }
        const double hd  = (double)h;
        const double nx  = -(beta[0] / hd);
        const double ny  = -(beta[1] / hd);
        const double nrm = sqrt(nx * nx + ny * ny + 1.0);
        out[b * 3 + 0] = (float)(nx / nrm);
        out[b * 3 + 1] = (float)(ny / nrm);
        out[b * 3 + 2] = (float)(1.0 / nrm);
    }
}

extern "C" void kernel_launch(void* const* d_in, const int* in_sizes, int n_in,
                              void* d_out, int out_size, void* d_ws, size_t ws_size,
                              hipStream_t stream) {
    const float* pts = (const float*)d_in[0];
    const float* W1  = (const float*)d_in[1];
    const float* b1  = (const float*)d_in[2];
    const float* W2  = (const float*)d_in[3];
    const float* b2  = (const float*)d_in[4];
    // d_in[5] = k (==40), compile-time constant here.
    float* wbuf = (float*)d_ws;   // [B*N] f32 = 512 KB scratch
    float* out  = (float*)d_out;  // [B,3] f32

    knn_weight_kernel<<<BB * (NN / 16), 256, 0, stream>>>(pts, W1, b1, W2, b2, wbuf);
    fit_kernel<<<BB, 256, 0, stream>>>(pts, wbuf, out);
}